// Round 5
// baseline (40.243 us; speedup 1.0000x reference)
//
#include <hip/hip_runtime.h>

// FK over the SMPL joint tree — double-buffered async-DMA pipeline.
// 512 single-wave blocks (64 threads = 64 frames/tile), grid-stride over
// 1568 tiles, 2 blocks/CU (2 x 33792 B LDS). Per iteration:
//   s_waitcnt vmcnt(33)  -> tile t's DMAs done (only prev stores outstanding;
//                           vmcnt never drains to 0 in the loop)
//   issue 33 global_load_lds dwordx4 for tile t+G into the other buffer
//   compute tile t in place (frame-per-thread, FK chain in registers)
//   ds_read_b128 + global_store_dwordx4 coalesced store of tile t
// Next tile's ~4200cy stage (latency+transfer) hides under compute+store.

#define FPB 64          // frames per tile == threads per block == 1 wave
#define TILE_FLOATS (FPB * 132)   // 8448 floats = 33792 B
#define CHUNKS 33       // 1024 B DMA chunks per tile

__device__ __forceinline__ void local_rot(const float* s, float* L) {
    float a1x = s[0], a1y = s[1], a1z = s[2];
    float a2x = s[3], a2y = s[4], a2z = s[5];
    float n1 = sqrtf(a1x * a1x + a1y * a1y + a1z * a1z);
    float i1 = 1.0f / fmaxf(n1, 1e-12f);
    float b1x = a1x * i1, b1y = a1y * i1, b1z = a1z * i1;
    float dt = b1x * a2x + b1y * a2y + b1z * a2z;
    float cx = a2x - dt * b1x, cy = a2y - dt * b1y, cz = a2z - dt * b1z;
    float n2 = sqrtf(cx * cx + cy * cy + cz * cz);
    float i2 = 1.0f / fmaxf(n2, 1e-12f);
    float b2x = cx * i2, b2y = cy * i2, b2z = cz * i2;
    L[0] = b1x; L[1] = b1y; L[2] = b1z;
    L[3] = b2x; L[4] = b2y; L[5] = b2z;
    L[6] = b1y * b2z - b1z * b2y;
    L[7] = b1z * b2x - b1x * b2z;
    L[8] = b1x * b2y - b1y * b2x;
}

// Full FK chain for one frame; src/dst alias safely (slot 6j written only
// after joint j's input is consumed; later joints never re-read inputs).
__device__ __forceinline__ void fk_frame(const float* src, float* dst) {
    constexpr int PAR[22] = {0, 0, 0, 0, 1, 2, 3, 4, 5, 6, 7, 8, 9, 9, 9,
                             12, 13, 14, 16, 17, 18, 19};
    float Rg[22][9];  // statically indexed after unroll -> registers
#pragma unroll
    for (int j = 0; j < 22; ++j) {
        float L[9];
        local_rot(src + 6 * j, L);
        float* G = Rg[j];
        if (j == 0) {
#pragma unroll
            for (int k = 0; k < 9; ++k) G[k] = L[k];
        } else {
            const float* P = Rg[PAR[j]];  // compile-time index
#pragma unroll
            for (int r = 0; r < 3; ++r)
#pragma unroll
                for (int c = 0; c < 3; ++c)
                    G[3 * r + c] = P[3 * r + 0] * L[0 + c] +
                                   P[3 * r + 1] * L[3 + c] +
                                   P[3 * r + 2] * L[6 + c];
        }
#pragma unroll
        for (int k = 0; k < 6; ++k) dst[6 * j + k] = G[k];
    }
}

__device__ __forceinline__ void stage_tile(const float* __restrict__ in,
                                           float* lbuf, int tile, int tid) {
    const float* gsrc = in + (size_t)tile * TILE_FLOATS;
#pragma unroll
    for (int k = 0; k < CHUNKS; ++k) {
        const float* src = gsrc + (size_t)(k * 64 + tid) * 4;
        float* dst = lbuf + k * 64 * 4;  // wave-uniform base; HW adds lane*16
        __builtin_amdgcn_global_load_lds(
            (const __attribute__((address_space(1))) void*)src,
            (__attribute__((address_space(3))) void*)dst, 16, 0, 0);
    }
}

__global__ __launch_bounds__(FPB) void fk6d_kernel(const float* __restrict__ in,
                                                   float* __restrict__ out,
                                                   int NT, int G)
{
    __shared__ float lds[2][TILE_FLOATS];  // 67584 B -> 2 blocks/CU
    const int tid = threadIdx.x;

    int t = blockIdx.x;
    if (t < NT) stage_tile(in, lds[0], t, tid);

    int cur = 0;
    bool first = true;
    for (; t < NT; t += G) {
        // wait for tile t's 33 DMAs; prev tile's 33 stores may stay in flight
        if (first) {
            asm volatile("s_waitcnt vmcnt(0)" ::: "memory");
            first = false;
        } else {
            asm volatile("s_waitcnt vmcnt(33)" ::: "memory");
        }

        int nxt = t + G;
        if (nxt < NT) stage_tile(in, lds[cur ^ 1], nxt, tid);
        // pin DMA issue order before compute/stores (keeps vmcnt count exact)
        asm volatile("" ::: "memory");

        // compute: one frame per thread, in place in its LDS row
        float* row = &lds[cur][tid * 132];
        fk_frame(row, row);

        // coalesced store-back
        float* gdst = out + (size_t)t * TILE_FLOATS;
#pragma unroll
        for (int k = 0; k < CHUNKS; ++k) {
            float4 v = *reinterpret_cast<const float4*>(&lds[cur][(k * 64 + tid) * 4]);
            *reinterpret_cast<float4*>(gdst + (size_t)(k * 64 + tid) * 4) = v;
        }
        cur ^= 1;
    }
}

// scalar tail (only launched if N % 64 != 0 — not the case for 512x196)
__global__ void fk6d_tail(const float* __restrict__ in, float* __restrict__ out,
                          int n0, int N) {
    int n = n0 + blockIdx.x * blockDim.x + threadIdx.x;
    if (n < N) fk_frame(in + (size_t)n * 132, out + (size_t)n * 132);
}

extern "C" void kernel_launch(void* const* d_in, const int* in_sizes, int n_in,
                              void* d_out, int out_size, void* d_ws, size_t ws_size,
                              hipStream_t stream) {
    const float* in = (const float*)d_in[0];
    float* out = (float*)d_out;
    int N = in_sizes[0] / 132;   // B*T frames = 100352
    int NT = N / FPB;            // full tiles = 1568
    int G = 512;                 // 2 blocks/CU on 256 CUs
    if (G > NT) G = (NT > 0 ? NT : 1);
    fk6d_kernel<<<G, FPB, 0, stream>>>(in, out, NT, G);
    int rem = N - NT * FPB;
    if (rem > 0) {
        fk6d_tail<<<(rem + 63) / 64, 64, 0, stream>>>(in, out, NT * FPB, N);
    }
}

// Round 6
// 26.568 us; speedup vs baseline: 1.5147x; 1.5147x over previous
//
#include <hip/hip_runtime.h>

// FK over the SMPL joint tree — half-frame lane split for 2x occupancy.
// Block = 128 threads = 2 waves; tile = 64 frames (33792 B LDS -> 4 blocks/CU
// = 8 waves/CU, 2x round-4's TLP). Wave w owns frames w*32..w*32+31:
//   lanes 0-31  (half A): joints 0-10 of frame (lane&31)
//   lanes 32-63 (half B): joints 11-21 of the same frame
// Joints 11-21 depend on 0-10 only via Rg[8], Rg[9] -> 18-float handoff via
// __shfl_xor(.,32), in-wave, no barrier. Gram-Schmidt (the expensive part)
// is lane-uniform (11 joints/lane); only the two chain-matmul sections are
// exec-masked. Staging: async global_load_lds dwordx4 (33 chunks split 17/16
// across waves), in-place output writeback, coalesced dwordx4 store.
// Compute-phase LDS conflicts drop 8-way -> 4-way (halves read cols m, m+66).

#define TPB 128
#define TILE_FRAMES 64
#define TILE_FLOATS (TILE_FRAMES * 132)  // 8448 floats = 33792 B = 33 chunks

__device__ __forceinline__ void local_rot(const float* s, float* L) {
    float a1x = s[0], a1y = s[1], a1z = s[2];
    float a2x = s[3], a2y = s[4], a2z = s[5];
    float n1 = sqrtf(a1x * a1x + a1y * a1y + a1z * a1z);
    float i1 = 1.0f / fmaxf(n1, 1e-12f);
    float b1x = a1x * i1, b1y = a1y * i1, b1z = a1z * i1;
    float dt = b1x * a2x + b1y * a2y + b1z * a2z;
    float cx = a2x - dt * b1x, cy = a2y - dt * b1y, cz = a2z - dt * b1z;
    float n2 = sqrtf(cx * cx + cy * cy + cz * cz);
    float i2 = 1.0f / fmaxf(n2, 1e-12f);
    float b2x = cx * i2, b2y = cy * i2, b2z = cz * i2;
    L[0] = b1x; L[1] = b1y; L[2] = b1z;
    L[3] = b2x; L[4] = b2y; L[5] = b2z;
    L[6] = b1y * b2z - b1z * b2y;
    L[7] = b1z * b2x - b1x * b2z;
    L[8] = b1x * b2y - b1y * b2x;
}

__device__ __forceinline__ void matmul3(float* G, const float* P, const float* L) {
#pragma unroll
    for (int r = 0; r < 3; ++r)
#pragma unroll
        for (int c = 0; c < 3; ++c)
            G[3 * r + c] = P[3 * r + 0] * L[0 + c] +
                           P[3 * r + 1] * L[3 + c] +
                           P[3 * r + 2] * L[6 + c];
}

__global__ __launch_bounds__(TPB, 2) void fk6d_kernel(const float* __restrict__ in,
                                                      float* __restrict__ out)
{
    __shared__ float lds[TILE_FLOATS];
    const int tid = threadIdx.x;
    const int wid = tid >> 6;          // wave 0 / wave 1
    const int lane = tid & 63;
    const int half = lane >> 5;        // 0: joints 0-10, 1: joints 11-21
    const int frame = (wid << 5) | (lane & 31);

    const float* gin = in + (size_t)blockIdx.x * TILE_FLOATS;
    float* gout = out + (size_t)blockIdx.x * TILE_FLOATS;

    // ---- async stage: 33 x 1024B chunks, wave0: 0-16, wave1: 17-32
    if (wid == 0) {
#pragma unroll
        for (int k = 0; k < 17; ++k)
            __builtin_amdgcn_global_load_lds(
                (const __attribute__((address_space(1))) void*)(gin + (k * 64 + lane) * 4),
                (__attribute__((address_space(3))) void*)(lds + k * 256), 16, 0, 0);
    } else {
#pragma unroll
        for (int k = 17; k < 33; ++k)
            __builtin_amdgcn_global_load_lds(
                (const __attribute__((address_space(1))) void*)(gin + (k * 64 + lane) * 4),
                (__attribute__((address_space(3))) void*)(lds + k * 256), 16, 0, 0);
    }
    __syncthreads();  // drains vmcnt before LDS reads

    float* row = lds + frame * 132;

    // ---- phase 1 (uniform): Gram-Schmidt for this lane's 11 joints
    float L[11][9];
    {
        const float* src = row + 66 * half;  // A: cols 0..65, B: cols 66..131
#pragma unroll
        for (int i = 0; i < 11; ++i) local_rot(src + 6 * i, L[i]);
    }

    // ---- phase 2 (half A): chain joints 0-10, write outs, extract Rg8/Rg9
    float e8[9], e9[9];
    if (half == 0) {
        float Rg[11][9];
        // local parents for joints 1..10: {0,0,0,1,2,3,4,5,6,7}
#pragma unroll
        for (int k = 0; k < 9; ++k) Rg[0][k] = L[0][k];
        matmul3(Rg[1], Rg[0], L[1]);
        matmul3(Rg[2], Rg[0], L[2]);
        matmul3(Rg[3], Rg[0], L[3]);
        matmul3(Rg[4], Rg[1], L[4]);
        matmul3(Rg[5], Rg[2], L[5]);
        matmul3(Rg[6], Rg[3], L[6]);
        matmul3(Rg[7], Rg[4], L[7]);
        matmul3(Rg[8], Rg[5], L[8]);
        matmul3(Rg[9], Rg[6], L[9]);
        matmul3(Rg[10], Rg[7], L[10]);
#pragma unroll
        for (int i = 0; i < 11; ++i)
#pragma unroll
            for (int k = 0; k < 6; ++k) row[6 * i + k] = Rg[i][k];
#pragma unroll
        for (int k = 0; k < 9; ++k) { e8[k] = Rg[8][k]; e9[k] = Rg[9][k]; }
    }

    // ---- phase 3 (uniform): hand Rg8/Rg9 from lanes l to lanes l+32
#pragma unroll
    for (int k = 0; k < 9; ++k) {
        e8[k] = __shfl_xor(e8[k], 32, 64);
        e9[k] = __shfl_xor(e9[k], 32, 64);
    }

    // ---- phase 4 (half B): chain joints 11-21 off e8/e9, write outs
    if (half == 1) {
        float Rg[11][9];  // local idx i = joint 11+i
        matmul3(Rg[0], e8, L[0]);       // j11 <- j8
        matmul3(Rg[1], e9, L[1]);       // j12 <- j9
        matmul3(Rg[2], e9, L[2]);       // j13 <- j9
        matmul3(Rg[3], e9, L[3]);       // j14 <- j9
        matmul3(Rg[4], Rg[1], L[4]);    // j15 <- j12
        matmul3(Rg[5], Rg[2], L[5]);    // j16 <- j13
        matmul3(Rg[6], Rg[3], L[6]);    // j17 <- j14
        matmul3(Rg[7], Rg[5], L[7]);    // j18 <- j16
        matmul3(Rg[8], Rg[6], L[8]);    // j19 <- j17
        matmul3(Rg[9], Rg[7], L[9]);    // j20 <- j18
        matmul3(Rg[10], Rg[8], L[10]);  // j21 <- j19
#pragma unroll
        for (int i = 0; i < 11; ++i)
#pragma unroll
            for (int k = 0; k < 6; ++k) row[66 + 6 * i + k] = Rg[i][k];
    }
    __syncthreads();

    // ---- coalesced store-back (b128), same 17/16 wave split
    if (wid == 0) {
#pragma unroll
        for (int k = 0; k < 17; ++k) {
            float4 v = *reinterpret_cast<const float4*>(lds + (k * 64 + lane) * 4);
            *reinterpret_cast<float4*>(gout + (size_t)(k * 64 + lane) * 4) = v;
        }
    } else {
#pragma unroll
        for (int k = 17; k < 33; ++k) {
            float4 v = *reinterpret_cast<const float4*>(lds + (k * 64 + lane) * 4);
            *reinterpret_cast<float4*>(gout + (size_t)(k * 64 + lane) * 4) = v;
        }
    }
}

// scalar tail (not taken for 512x196: 100352 % 64 == 0)
__device__ __forceinline__ void fk_frame_full(const float* src, float* dst) {
    constexpr int PAR[22] = {0, 0, 0, 0, 1, 2, 3, 4, 5, 6, 7, 8, 9, 9, 9,
                             12, 13, 14, 16, 17, 18, 19};
    float Rg[22][9];
#pragma unroll
    for (int j = 0; j < 22; ++j) {
        float Lr[9];
        local_rot(src + 6 * j, Lr);
        if (j == 0) {
#pragma unroll
            for (int k = 0; k < 9; ++k) Rg[0][k] = Lr[k];
        } else {
            matmul3(Rg[j], Rg[PAR[j]], Lr);
        }
#pragma unroll
        for (int k = 0; k < 6; ++k) dst[6 * j + k] = Rg[j][k];
    }
}

__global__ void fk6d_tail(const float* __restrict__ in, float* __restrict__ out,
                          int n0, int N) {
    int n = n0 + blockIdx.x * blockDim.x + threadIdx.x;
    if (n < N) fk_frame_full(in + (size_t)n * 132, out + (size_t)n * 132);
}

extern "C" void kernel_launch(void* const* d_in, const int* in_sizes, int n_in,
                              void* d_out, int out_size, void* d_ws, size_t ws_size,
                              hipStream_t stream) {
    const float* in = (const float*)d_in[0];
    float* out = (float*)d_out;
    int N = in_sizes[0] / 132;       // 100352 frames
    int NT = N / TILE_FRAMES;        // 1568 full tiles
    if (NT > 0) fk6d_kernel<<<NT, TPB, 0, stream>>>(in, out);
    int rem = N - NT * TILE_FRAMES;
    if (rem > 0)
        fk6d_tail<<<(rem + 63) / 64, 64, 0, stream>>>(in, out, NT * TILE_FRAMES, N);
}